// Round 10
// baseline (25538.165 us; speedup 1.0000x reference)
//
#include <hip/hip_runtime.h>
#include <math.h>

#define NBLK    32          // worker blocks, all on ONE XCD (its 32 CUs)
#define NLAUNCH 256         // launched blocks; non-elected exit immediately
#define BS      512
#define NSTATE  17
#define NH      256
#define NX      273         // NH + NSTATE
#define WID     1024
#define NT      64
#define NSUB    8
#define ROWS_H  (WID/NBLK)  // 32 rows/block for 1024-wide layers
#define ROWS_L  (NH/NBLK)   // 8 rows/block for the 256-wide output layer
#define POLL_CAP 2000000    // fail fast instead of hanging

typedef unsigned long long u64;
typedef unsigned int u32;

__device__ __forceinline__ float softplus_f(float v) {
    return fmaxf(v, 0.f) + log1pf(expf(-fabsf(v)));
}

// ---- sentinel-gated atomic-publish / plain-read exchange (same-XCD L2) ----
// Ledger: data STORES must be atomic swaps (plain stores are latently stale:
// R4/R6 absmax drift; atomic transport bit-exact in R1/R5/R9). Data READS
// were the cost: R9's retry sweeps kept ~16K RMWs in flight (~3 iterations).
// R10 protocol:
//   producer: 16 packed swaps (fire) -> per-wave vmcnt(0) (ack = executed
//             at L2) -> barrier -> ONE sentinel swap sent[blk] (own line).
//   consumer: lanes t<32 poll one sentinel each (32 in-flight, distinct
//             producer lines, self-draining -> no R6/R7 hot-line convoy)
//             -> barrier -> buffer_inv (L1-only; data is IN L2 by the
//             sentinel's ordering) -> ONE plain dwordx2 load per word ->
//             tag-check with atomic-retry fallback (correctness insurance).
// Payload: 2 rows bf16(RNE) in lo32, hi32 = tag ^ lo32 (tear/stale-proof);
// dh stays f32. Tag = tagbase(launch nonce) + monotone round R.
__device__ __forceinline__ u32 bf16_rne(float x) {
    u32 u = __float_as_uint(x);
    return (u + 0x7FFFu + ((u >> 16) & 1u)) >> 16;
}
__device__ __forceinline__ void st_pack(u64* p, float ve, float vo, unsigned tag) {
    u32 lo = (bf16_rne(ve) << 16) | bf16_rne(vo);
    u64 w = ((u64)(tag ^ lo) << 32) | (u64)lo;
    asm volatile("global_atomic_swap_x2 %0, %1, off" :: "v"(p), "v"(w) : "memory");
}
__device__ __forceinline__ void st_tag(u64* p, float v, unsigned tag) {
    u32 lo = __float_as_uint(v);
    u64 w = ((u64)(tag ^ lo) << 32) | (u64)lo;
    asm volatile("global_atomic_swap_x2 %0, %1, off" :: "v"(p), "v"(w) : "memory");
}
__device__ __forceinline__ u64 ld_tag(const u64* p) {
    u64 w;
    asm volatile("global_atomic_add_x2 %0, %1, %2, off sc0\n\t"
                 "s_waitcnt vmcnt(0)"
                 : "=&v"(w) : "v"(p), "v"(0ULL) : "memory");
    return w;
}
__device__ __forceinline__ bool tag_ok(u64 w, unsigned tag) {
    return (((u32)(w >> 32)) ^ ((u32)w)) == tag;
}

#define SENT_STRIDE 16   // u64s -> 128B: one sentinel per producer per line

// producer epilogue: per-wave swap-ack, block barrier, sentinel swap
__device__ __forceinline__ void publish_fence(u64* sent, int blk, unsigned tag, int t) {
    asm volatile("s_waitcnt vmcnt(0)" ::: "memory");   // swaps executed at L2
    __syncthreads();
    if (t == 0) st_tag(sent + blk * SENT_STRIDE, 0.f, tag);
}
// consumer prologue: sentinel detect + L1 invalidate
__device__ __forceinline__ void wait_sent(const u64* sent, unsigned tag, int t) {
    if (t < NBLK) {
        const u64* sp = sent + t * SENT_STRIDE;
        u64 w; int it = 0;
        do { w = ld_tag(sp); } while (!tag_ok(w, tag) && ++it < POLL_CAP);
    }
    __syncthreads();
    asm volatile("buffer_inv" ::: "memory");           // L1-only inv; L2 is truth
}
// gather the 512-packed-word buffer into z_s[1024]; one plain load per thread
__device__ __forceinline__ void consume_z(const u64* __restrict__ buf,
                                          const u64* __restrict__ sent,
                                          unsigned tag,
                                          float* __restrict__ z_s, int t) {
    wait_sent(sent, tag, t);
    u64 w = buf[t];                    // plain load: L1 miss -> L2 (fresh)
    if (!tag_ok(w, tag)) {             // paranoia fallback, exact either way
        int it = 0;
        do { w = ld_tag(buf + t); } while (!tag_ok(w, tag) && ++it < POLL_CAP);
    }
    u32 lo = (u32)w;
    z_s[2 * t]     = __uint_as_float(lo & 0xFFFF0000u);
    z_s[2 * t + 1] = __uint_as_float(lo << 16);
    __syncthreads();
}

extern "C" __global__ __launch_bounds__(BS, 2) void ode_kernel(
    const float* __restrict__ ts,   const float* __restrict__ W0,
    const float* __restrict__ b0,   const float* __restrict__ Wh,
    const float* __restrict__ bh,   const float* __restrict__ Wl,
    const float* __restrict__ bl,   const float* __restrict__ betaW,
    const float* __restrict__ betab,const float* __restrict__ hvec,
    const float* __restrict__ scale,const float* __restrict__ y0log,
    float* __restrict__ out, u64* zA64, u64* zB64, u64* dh64,
    u64* sent, unsigned* ctrl)
{
    const int t = threadIdx.x;

    __shared__ int      role_sh;
    __shared__ unsigned tagbase_sh;
    __shared__ float y_s[NX];
    __shared__ float yn_s[NX];
    __shared__ float xm[NX];     // MLP-ordered input: [h(256), state(17)]
    __shared__ float k_s[NX];
    __shared__ float z_s[WID];
    __shared__ float red[8];
    __shared__ float dt_sh;
    extern __shared__ float wh2[];   // dynamic: 32 rows x 1024 of layer-3 (128 KB)

    // ---- XCD election (MALL atomics, one-time): first XCD to register NBLK
    // blocks wins. ~137KB LDS -> 1 block/CU; all 256 launched co-resident.
    // Winner word packs {realtime-nonce:28 | xcd+1:4}; doubles as tag base.
    if (t == 0) {
        int xcd;
        asm volatile("s_getreg_b32 %0, hwreg(HW_REG_XCC_ID)" : "=s"(xcd));
        xcd &= 7;
        unsigned rk = atomicAdd(&ctrl[xcd], 1u);
        if (rk == NBLK - 1) {
            u64 rt;
            asm volatile("s_memrealtime %0\n\ts_waitcnt lgkmcnt(0)" : "=s"(rt));
            unsigned word = (((unsigned)(rt >> 4)) << 4) | (unsigned)(xcd + 1);
            atomicCAS(&ctrl[8], 0u, word);
        }
        unsigned w; int it = 0;
        do {
            w = __hip_atomic_load(&ctrl[8], __ATOMIC_RELAXED, __HIP_MEMORY_SCOPE_AGENT);
        } while (w == 0u && ++it < POLL_CAP);
        role_sh    = (w != 0u && xcd == (int)(w & 0xFu) - 1 && rk < NBLK) ? (int)rk : -1;
        tagbase_sh = w;
    }
    __syncthreads();
    const int blk = role_sh;
    const unsigned tagbase = tagbase_sh;
    if (blk < 0) return;

    const float scale0 = scale[0];
    const float betab0 = betab[0];
    unsigned R = 0;   // exchange round; identical sequence on all workers

    const int rowH = t >> 4, laneH = t & 15;
    const int growH = blk * ROWS_H + rowH;
    const int rowL = t >> 6, laneL = t & 63;
    const int growL = blk * ROWS_L + rowL;

    // packed word index for this thread's (even) row pair
    const int packIdx = blk * (ROWS_H / 2) + (rowH >> 1);

    // ---- loop-invariant scalars ----
    const float b0r = b0[growH];
    float bhr[3];
    bhr[0] = bh[growH]; bhr[1] = bh[WID + growH]; bhr[2] = bh[2 * WID + growH];
    const float blr    = bl[growL];
    const float betaWr = (t < NH) ? betaW[t] : 0.f;
    const float* wlp = Wl + (size_t)growL * WID + laneL * 4;

    // ---- weight residency: h1,h2 in VGPR/AGPR (proven R5/R9), h3 slice in
    //      LDS (128KB), W0 in 18 regs, Wl streamed (L2-resident).
    float4 wv0[16], wv1[16];
    {
        const float* whp = Wh + (size_t)growH * WID + laneH * 4;
        #pragma unroll
        for (int i = 0; i < 16; i++) wv0[i] = *(const float4*)(whp + i * 64);
        #pragma unroll
        for (int i = 0; i < 16; i++) wv1[i] = *(const float4*)(whp + WID * WID + i * 64);
    }
    {   // copy layer-3 row slice into LDS (coalesced float4)
        const float* src = Wh + 2 * (size_t)WID * WID + (size_t)blk * ROWS_H * WID;
        for (int i = t * 4; i < ROWS_H * WID; i += BS * 4)
            *(float4*)&wh2[i] = *(const float4*)&src[i];
    }
    float w0r[18];
    {
        const float* w0p = W0 + (size_t)growH * NX;
        #pragma unroll
        for (int i = 0; i < 18; i++) {
            int c = laneH + i * 16;
            w0r[i] = (c < NX) ? w0p[c] : 0.f;
        }
    }

    // ---- y0 = [softmax(y0_log), hvec] ----
    if (t < NSTATE) {
        float m = -1e30f;
        for (int j = 0; j < NSTATE; j++) m = fmaxf(m, y0log[j]);
        float ssum = 0.f;
        for (int j = 0; j < NSTATE; j++) ssum += expf(y0log[j] - m);
        y_s[t] = expf(y0log[t] - m) / ssum;
    }
    if (t < NH) y_s[NSTATE + t] = hvec[t];
    __syncthreads();

    if (blk == 0) {
        if (t < NSTATE) out[t] = y_s[t];
        if (t < NH)     out[NT * NSTATE + t] = y_s[NSTATE + t];
    }

    const float c_xi = 13.f / 12.f, c_mu = 0.041f / 12.f, c_sig = 91.f / 12.f,
                c_nu = 36.f / 12.f, c_gam = 1.8f / 12.f;

    for (int iv = 0; iv < NT - 1; iv++) {
        if (t == 0) dt_sh = (ts[iv + 1] - ts[iv]) * (1.f / NSUB);
        __syncthreads();
        const float dt = dt_sh;

        for (int sub = 0; sub < NSUB; sub++) {
            if (t < NX) yn_s[t] = y_s[t];

            for (int s = 0; s < 4; s++) {
                const float a   = (s == 0) ? 0.f : ((s == 3) ? 1.f : 0.5f);
                const float wgt = ((s == 0) || (s == 3)) ? dt * (1.f / 6.f) : dt * (1.f / 3.f);
                const float adt = a * dt;

                // ---- stage input, built directly in MLP order [h, state] ----
                if (t < NX) {
                    const int src = (t < NH) ? (NSTATE + t) : (t - NH);
                    float v = y_s[src];
                    if (s != 0) v = fmaf(adt, k_s[src], v);
                    xm[t] = v;
                }
                __syncthreads();

                // ---- L0: 1024x273, W0 in regs (fmaf-pinned) ----
                {
                    float acc = 0.f;
                    #pragma unroll
                    for (int i = 0; i < 18; i++) {
                        int c = laneH + i * 16;
                        if (c < NX) acc = fmaf(w0r[i], xm[c], acc);
                    }
                    #pragma unroll
                    for (int m = 1; m < 16; m <<= 1) acc += __shfl_xor(acc, m, 16);
                    float val = softplus_f(acc + b0r);
                    float vodd = __shfl(val, (t & 63) + 16, 64); // next row's val
                    ++R;
                    if ((t & 31) == 0) st_pack(&zA64[packIdx], val, vodd, tagbase + R);
                }

                // ---- beta head: VALU work overlapping the swap flight ----
                if (t < NH) {
                    float p = betaWr * xm[t];
                    #pragma unroll
                    for (int m = 1; m < 64; m <<= 1) p += __shfl_xor(p, m, 64);
                    if ((t & 63) == 0) red[t >> 6] = p;
                }
                // publish fence (ack + barrier also publishes red[]) + sentinel
                publish_fence(sent, blk, tagbase + R, t);

                // ---- dstate on t==256 (wave 4): wave 0 polls concurrently ----
                if (t == 256) {
                    const float* xs = xm + NH;
                    float sd  = red[0] + red[1] + red[2] + red[3] + betab0;
                    float bb1 = 8.f / (1.f + expf(-sd)) + 25.f;
                    float bb2 = 0.5f * bb1, bb3 = 0.35f * bb1, bb4 = 0.25f * bb1;
                    float M  = xs[0],  S1 = xs[1],  E1 = xs[2],  E2 = xs[3];
                    float E3 = xs[4],  E4 = xs[5],  I1 = xs[6],  I2 = xs[7];
                    float I3 = xs[8],  I4 = xs[9],  R1 = xs[10], R2 = xs[11];
                    float R3 = xs[12], R4 = xs[13], S2 = xs[14], S3 = xs[15];
                    float S4 = xs[16];
                    float I = I1 + I2 + I3 + I4, Rs = R1 + R2 + R3 + R4;
                    k_s[0]  = Rs * c_mu - (c_xi + c_mu) * M;
                    k_s[1]  = c_mu * (1.f - Rs) + c_xi * M - c_mu * S1 - bb1 * I * S1;
                    k_s[2]  = bb1 * I * S1 - (c_mu + c_sig) * E1;
                    k_s[3]  = bb2 * I * S2 - (c_mu + c_sig) * E2;
                    k_s[4]  = bb3 * I * S3 - (c_mu + c_sig) * E3;
                    k_s[5]  = bb4 * I * S4 - (c_mu + c_sig) * E4;
                    k_s[6]  = c_sig * E1 - (c_nu + c_mu) * I1;
                    k_s[7]  = c_sig * E2 - (c_nu + c_mu) * I2;
                    k_s[8]  = c_sig * E3 - (c_nu + c_mu) * I3;
                    k_s[9]  = c_sig * E4 - (c_nu + c_mu) * I4;
                    k_s[10] = c_nu * I1 - (c_mu + c_gam) * R1;
                    k_s[11] = c_nu * I2 - (c_mu + c_gam) * R2;
                    k_s[12] = c_nu * I3 - (c_mu + c_gam) * R3;
                    k_s[13] = c_nu * I4 - (c_mu + c_gam) * R4;
                    k_s[14] = c_gam * R1 - c_mu * S2 - bb2 * I * S2;
                    k_s[15] = c_gam * R2 - c_mu * S3 - bb3 * I * S3;
                    k_s[16] = c_gam * (R3 + R4) - c_mu * S4 - bb4 * I * S4;
                }
                // k_s[0..16] next read only after later consume barriers.

                // ---- h1, h2: weights in registers (fmaf-pinned) ----
                auto hidden = [&](const float4 (&wv)[16], const u64* zin64,
                                  u64* zout64, float bias) {
                    consume_z(zin64, sent, tagbase + R, z_s, t);
                    float acc = 0.f;
                    #pragma unroll
                    for (int i = 0; i < 16; i++) {
                        float4 zv = *(const float4*)(z_s + (laneH * 4 + i * 64));
                        acc = fmaf(wv[i].x, zv.x, acc);
                        acc = fmaf(wv[i].y, zv.y, acc);
                        acc = fmaf(wv[i].z, zv.z, acc);
                        acc = fmaf(wv[i].w, zv.w, acc);
                    }
                    #pragma unroll
                    for (int m = 1; m < 16; m <<= 1) acc += __shfl_xor(acc, m, 16);
                    float val = softplus_f(acc + bias);
                    float vodd = __shfl(val, (t & 63) + 16, 64);
                    ++R;
                    if ((t & 31) == 0) st_pack(&zout64[packIdx], val, vodd, tagbase + R);
                    publish_fence(sent, blk, tagbase + R, t);
                };

                hidden(wv0, zA64, zB64, bhr[0]);
                hidden(wv1, zB64, zA64, bhr[1]);

                // prefetch Wl row slice (L2-resident); overlaps h3 exchange
                float4 wvL[4];
                #pragma unroll
                for (int i = 0; i < 4; i++) wvL[i] = *(const float4*)(wlp + i * 256);

                // ---- h3: weights from LDS (fmaf-pinned) ----
                {
                    consume_z(zA64, sent, tagbase + R, z_s, t);
                    const float* wr = wh2 + rowH * WID + laneH * 4;
                    float acc = 0.f;
                    #pragma unroll
                    for (int i = 0; i < 16; i++) {
                        float4 wv4 = *(const float4*)(wr + i * 64);
                        float4 zv  = *(const float4*)(z_s + (laneH * 4 + i * 64));
                        acc = fmaf(wv4.x, zv.x, acc);
                        acc = fmaf(wv4.y, zv.y, acc);
                        acc = fmaf(wv4.z, zv.z, acc);
                        acc = fmaf(wv4.w, zv.w, acc);
                    }
                    #pragma unroll
                    for (int m = 1; m < 16; m <<= 1) acc += __shfl_xor(acc, m, 16);
                    float val = softplus_f(acc + bhr[2]);
                    float vodd = __shfl(val, (t & 63) + 16, 64);
                    ++R;
                    if ((t & 31) == 0) st_pack(&zB64[packIdx], val, vodd, tagbase + R);
                    publish_fence(sent, blk, tagbase + R, t);
                }

                // ---- Wl: 256x1024, 8 rows/block; tanh; dh published f32 ----
                {
                    consume_z(zB64, sent, tagbase + R, z_s, t);
                    float acc = 0.f;
                    #pragma unroll
                    for (int i = 0; i < 4; i++) {
                        float4 zv = *(const float4*)(z_s + (laneL * 4 + i * 256));
                        acc = fmaf(wvL[i].x, zv.x, acc);
                        acc = fmaf(wvL[i].y, zv.y, acc);
                        acc = fmaf(wvL[i].z, zv.z, acc);
                        acc = fmaf(wvL[i].w, zv.w, acc);
                    }
                    #pragma unroll
                    for (int m = 1; m < 64; m <<= 1) acc += __shfl_xor(acc, m, 64);
                    ++R;
                    if (laneL == 0)
                        st_tag(&dh64[growL], scale0 * tanhf(0.01f * (acc + blr)), tagbase + R);
                    publish_fence(sent, blk, tagbase + R, t);
                }

                // ---- gather dh (f32): sentinel-gated single plain read ----
                {
                    wait_sent(sent, tagbase + R, t);
                    if (t < NH) {
                        u64 w = dh64[t];
                        if (!tag_ok(w, tagbase + R)) {
                            int it = 0;
                            do { w = ld_tag(dh64 + t); }
                            while (!tag_ok(w, tagbase + R) && ++it < POLL_CAP);
                        }
                        k_s[NSTATE + t] = __uint_as_float((u32)w);
                    }
                    __syncthreads();
                    if (t < NX) yn_s[t] = fmaf(wgt, k_s[t], yn_s[t]);
                }
            } // stages

            __syncthreads();
            if (t < NX) y_s[t] = yn_s[t];
            __syncthreads();
        } // substeps

        if (blk == 0) {
            if (t < NSTATE) out[(iv + 1) * NSTATE + t] = y_s[t];
            if (t < NH)     out[NT * NSTATE + (iv + 1) * NH + t] = y_s[NSTATE + t];
        }
    } // intervals
}

extern "C" void kernel_launch(void* const* d_in, const int* in_sizes, int n_in,
                              void* d_out, int out_size, void* d_ws, size_t ws_size,
                              hipStream_t stream) {
    const float* ts    = (const float*)d_in[0];
    const float* W0    = (const float*)d_in[1];
    const float* b0    = (const float*)d_in[2];
    const float* Wh    = (const float*)d_in[3];
    const float* bh    = (const float*)d_in[4];
    const float* Wl    = (const float*)d_in[5];
    const float* bl    = (const float*)d_in[6];
    const float* betaW = (const float*)d_in[7];
    const float* betab = (const float*)d_in[8];
    const float* hvec  = (const float*)d_in[9];
    const float* scale = (const float*)d_in[10];
    const float* y0log = (const float*)d_in[11];
    float* out = (float*)d_out;

    u64*      zA64 = (u64*)d_ws;                          // 512*8 = 4 KB
    u64*      zB64 = (u64*)((char*)d_ws + 4096);          // 4 KB
    u64*      dh64 = (u64*)((char*)d_ws + 8192);          // 256*8 = 2 KB
    u64*      sent = (u64*)((char*)d_ws + 10240);         // 32 x 128B = 4 KB
    unsigned* ctrl = (unsigned*)((char*)d_ws + 14336);    // cnt[8], winner word

    // allow 128KB dynamic LDS (h3 weight slice)
    static int lds_set = 0;
    if (!lds_set) {
        hipFuncSetAttribute((const void*)ode_kernel,
                            hipFuncAttributeMaxDynamicSharedMemorySize, 131072);
        lds_set = 1;
    }

    // zero tagged words + sentinels + election state (tag 0 never matches)
    hipMemsetAsync(d_ws, 0, 14336 + 64, stream);
    hipLaunchKernelGGL(ode_kernel, dim3(NLAUNCH), dim3(BS), 131072, stream,
                       ts, W0, b0, Wh, bh, Wl, bl, betaW, betab, hvec, scale,
                       y0log, out, zA64, zB64, dh64, sent, ctrl);
}

// Round 11
// 23757.352 us; speedup vs baseline: 1.0750x; 1.0750x over previous
//
#include <hip/hip_runtime.h>
#include <math.h>

#define NBLK    32          // worker blocks, all on ONE XCD (its 32 CUs)
#define NLAUNCH 256         // launched blocks; non-elected exit immediately
#define BS      512
#define NSTATE  17
#define NH      256
#define NX      273         // NH + NSTATE
#define WID     1024
#define NT      64
#define NSUB    8
#define SLC     32          // activation slice per block = WID/NBLK
#define POLL_CAP 2000000    // fail fast instead of hanging

// fixed-point scales: value lives in bits 16..63 (int48), counter in bits 0..15
#define SCALE_H 16777216.0f             // 2^24 (h pre-act; headroom to 2^23)
#define INV_H   5.9604644775390625e-8f
#define SCALE_D 1048576.0f              // 2^20 (dh pre-act; running total <= 2^41)
#define INV_D   9.5367431640625e-7f

typedef unsigned long long u64;
typedef unsigned int u32;

__device__ __forceinline__ float softplus_f(float v) {
    return fmaxf(v, 0.f) + log1pf(expf(-fabsf(v)));
}

// ---- counter-embedded fixed-point accumulate exchange (same-XCD L2) -------
// Column-parallel partial sums: each block adds (q<<16)+1 into a layer word;
// int adds are associative -> deterministic. count==32 (low 16 bits) IS the
// arrival signal -- the add self-announces, no fences/sentinels/tags needed.
// All traffic via L2 atomic units (never stale, R5/R9-proven). h-buffers are
// swap-reset by their single consumer each round (vmcnt-fenced; next-round
// adds are transitively ordered after the reset via the dh sync). dh keeps a
// running total (32 readers): counter = 32*stage <= 64512, never wraps; no
// carry ever crosses bit 15 (counts only increment).
__device__ __forceinline__ void acc_add(u64* p, float v, float scale) {
    long long q = llrintf(v * scale);
    u64 w = ((u64)q << 16) + 1ULL;
    asm volatile("global_atomic_add_x2 %0, %1, off" :: "v"(p), "v"(w) : "memory");
}
__device__ __forceinline__ u64 rmw_read(const u64* p) {
    u64 w;
    asm volatile("global_atomic_add_x2 %0, %1, %2, off sc0\n\t"
                 "s_waitcnt vmcnt(0)"
                 : "=&v"(w) : "v"(p), "v"(0ULL) : "memory");
    return w;
}
__device__ __forceinline__ void reset_word(u64* p) {
    asm volatile("global_atomic_swap_x2 %0, %1, off" :: "v"(p), "v"(0ULL) : "memory");
}

extern "C" __global__ __launch_bounds__(BS, 1) void ode_kernel(
    const float* __restrict__ ts,   const float* __restrict__ W0,
    const float* __restrict__ b0,   const float* __restrict__ Wh,
    const float* __restrict__ bh,   const float* __restrict__ Wl,
    const float* __restrict__ bl,   const float* __restrict__ betaW,
    const float* __restrict__ betab,const float* __restrict__ hvec,
    const float* __restrict__ scale,const float* __restrict__ y0log,
    float* __restrict__ out, u64* hacc1, u64* hacc2, u64* hacc3,
    u64* dhacc, unsigned* ctrl)
{
    const int t = threadIdx.x;

    __shared__ int role_sh;
    __shared__ __align__(16) float y_s[NX];
    __shared__ __align__(16) float yn_s[NX];
    __shared__ __align__(16) float xm[NX];    // MLP order: [h(256), state(17)]
    __shared__ __align__(16) float k_s[NX];
    __shared__ __align__(16) float z1_s[SLC];
    __shared__ __align__(16) float h1_s[SLC];
    __shared__ __align__(16) float h2_s[SLC];
    __shared__ __align__(16) float h3_s[SLC];
    __shared__ float red[8];
    __shared__ float dt_sh;
    extern __shared__ float wh3c[];  // 128KB: col-major [j][r] = Wh[2][r][blk*32+j]

    // ---- XCD election (MALL atomics, one-time): first XCD with NBLK blocks
    // wins. ~134KB LDS -> 1 block/CU; all 256 launched blocks co-resident.
    if (t == 0) {
        int xcd;
        asm volatile("s_getreg_b32 %0, hwreg(HW_REG_XCC_ID)" : "=s"(xcd));
        xcd &= 7;
        unsigned rk = atomicAdd(&ctrl[xcd], 1u);
        if (rk == NBLK - 1) atomicCAS(&ctrl[8], 0u, (unsigned)(xcd + 1));
        unsigned w; int it = 0;
        do {
            w = __hip_atomic_load(&ctrl[8], __ATOMIC_RELAXED, __HIP_MEMORY_SCOPE_AGENT);
        } while (w == 0u && ++it < POLL_CAP);
        role_sh = (w != 0u && xcd == (int)w - 1 && rk < NBLK) ? (int)rk : -1;
    }
    __syncthreads();
    const int blk = role_sh;
    if (blk < 0) return;

    const float scale0 = scale[0];
    const float betab0 = betab[0];

    const int rowH = t >> 4, laneH = t & 15;   // 32 rows x 16 lanes (z1 only)
    const int growH = blk * SLC + rowH;

    // ---- loop-invariant scalars ----
    const float b0r    = b0[growH];
    const float betaWr = (t < NH) ? betaW[t] : 0.f;
    const float blr    = (t < NH) ? bl[t] : 0.f;
    float bhc[3];      // consume biases, threads t<32: row blk*32+t of layer l
    if (t < SLC) {
        bhc[0] = bh[blk * SLC + t];
        bhc[1] = bh[WID + blk * SLC + t];
        bhc[2] = bh[2 * WID + blk * SLC + t];
    }

    // ---- weights ----
    // W0 row-slice (z1 is computed locally, rows [blk*32, blk*32+32))
    float w0r[18];
    {
        const float* w0p = W0 + (size_t)growH * NX;
        #pragma unroll
        for (int i = 0; i < 18; i++) {
            int c = laneH + i * 16;
            w0r[i] = (c < NX) ? w0p[c] : 0.f;
        }
    }
    // h1/h2 COLUMN stripes in VGPRs: thread t owns output rows {t, t+512},
    // input cols [blk*32, blk*32+32): 4x8 float4 = 128 VGPR.
    float4 wc1a[8], wc1b[8], wc2a[8], wc2b[8];
    {
        const float* base0 = Wh + (size_t)t * WID + blk * SLC;
        const float* base1 = Wh + (size_t)(t + 512) * WID + blk * SLC;
        #pragma unroll
        for (int q = 0; q < 8; q++) {
            wc1a[q] = *(const float4*)(base0 + q * 4);
            wc1b[q] = *(const float4*)(base1 + q * 4);
            wc2a[q] = *(const float4*)(base0 + (size_t)WID * WID + q * 4);
            wc2b[q] = *(const float4*)(base1 + (size_t)WID * WID + q * 4);
        }
    }
    // h3 column stripe in LDS, col-major [j][r] (conflict-free partial reads)
    {
        const float* src = Wh + 2 * (size_t)WID * WID;
        for (int i = t; i < WID * 8; i += BS) {
            int r = i >> 3, q = i & 7;
            float4 v = *(const float4*)(src + (size_t)r * WID + blk * SLC + q * 4);
            wh3c[(q * 4 + 0) * WID + r] = v.x;
            wh3c[(q * 4 + 1) * WID + r] = v.y;
            wh3c[(q * 4 + 2) * WID + r] = v.z;
            wh3c[(q * 4 + 3) * WID + r] = v.w;
        }
    }

    // ---- y0 = [softmax(y0_log), hvec] ----
    if (t < NSTATE) {
        float m = -1e30f;
        for (int j = 0; j < NSTATE; j++) m = fmaxf(m, y0log[j]);
        float ssum = 0.f;
        for (int j = 0; j < NSTATE; j++) ssum += expf(y0log[j] - m);
        y_s[t] = expf(y0log[t] - m) / ssum;
    }
    if (t < NH) y_s[NSTATE + t] = hvec[t];
    __syncthreads();

    if (blk == 0) {
        if (t < NSTATE) out[t] = y_s[t];
        if (t < NH)     out[NT * NSTATE + t] = y_s[NSTATE + t];
    }

    const float c_xi = 13.f / 12.f, c_mu = 0.041f / 12.f, c_sig = 91.f / 12.f,
                c_nu = 36.f / 12.f, c_gam = 1.8f / 12.f;

    long long prev_dh = 0;   // running-total tracker for dh word t (t<NH)
    unsigned sidx = 0;       // global stage counter (dh count target = 32*sidx)

    for (int iv = 0; iv < NT - 1; iv++) {
        if (t == 0) dt_sh = (ts[iv + 1] - ts[iv]) * (1.f / NSUB);
        __syncthreads();
        const float dt = dt_sh;

        for (int sub = 0; sub < NSUB; sub++) {
            if (t < NX) yn_s[t] = y_s[t];

            for (int s = 0; s < 4; s++) {
                const float a   = (s == 0) ? 0.f : ((s == 3) ? 1.f : 0.5f);
                const float wgt = ((s == 0) || (s == 3)) ? dt * (1.f / 6.f) : dt * (1.f / 3.f);
                const float adt = a * dt;
                ++sidx;

                // ---- stage input, built directly in MLP order [h, state] ----
                if (t < NX) {
                    const int src = (t < NH) ? (NSTATE + t) : (t - NH);
                    float v = y_s[src];
                    if (s != 0) v = fmaf(adt, k_s[src], v);
                    xm[t] = v;
                }
                __syncthreads();                                   // B1

                // ---- z1 slice (local, no exchange): 32 rows x 16 lanes ----
                {
                    float acc = 0.f;
                    #pragma unroll
                    for (int i = 0; i < 18; i++) {
                        int c = laneH + i * 16;
                        if (c < NX) acc = fmaf(w0r[i], xm[c], acc);
                    }
                    #pragma unroll
                    for (int m = 1; m < 16; m <<= 1) acc += __shfl_xor(acc, m, 16);
                    if (laneH == 0) z1_s[rowH] = softplus_f(acc + b0r);
                }
                // beta head partial (independent of z1)
                if (t < NH) {
                    float p = betaWr * xm[t];
                    #pragma unroll
                    for (int m = 1; m < 64; m <<= 1) p += __shfl_xor(p, m, 64);
                    if ((t & 63) == 0) red[t >> 6] = p;
                }
                __syncthreads();                                   // B2

                // ---- h1 partial adds (fire-and-forget, self-announcing) ----
                {
                    float p0 = 0.f, p1 = 0.f;
                    #pragma unroll
                    for (int q = 0; q < 8; q++) {
                        float4 z = *(const float4*)(z1_s + q * 4);
                        p0 = fmaf(wc1a[q].x, z.x, p0); p0 = fmaf(wc1a[q].y, z.y, p0);
                        p0 = fmaf(wc1a[q].z, z.z, p0); p0 = fmaf(wc1a[q].w, z.w, p0);
                        p1 = fmaf(wc1b[q].x, z.x, p1); p1 = fmaf(wc1b[q].y, z.y, p1);
                        p1 = fmaf(wc1b[q].z, z.z, p1); p1 = fmaf(wc1b[q].w, z.w, p1);
                    }
                    acc_add(hacc1 + t, p0, SCALE_H);
                    acc_add(hacc1 + t + 512, p1, SCALE_H);
                }

                // ---- dstate (redundant, one thread; overlaps h1 flight) ----
                if (t == 256) {
                    const float* xs = xm + NH;
                    float sd  = red[0] + red[1] + red[2] + red[3] + betab0;
                    float bb1 = 8.f / (1.f + expf(-sd)) + 25.f;
                    float bb2 = 0.5f * bb1, bb3 = 0.35f * bb1, bb4 = 0.25f * bb1;
                    float M  = xs[0],  S1 = xs[1],  E1 = xs[2],  E2 = xs[3];
                    float E3 = xs[4],  E4 = xs[5],  I1 = xs[6],  I2 = xs[7];
                    float I3 = xs[8],  I4 = xs[9],  R1 = xs[10], R2 = xs[11];
                    float R3 = xs[12], R4 = xs[13], S2 = xs[14], S3 = xs[15];
                    float S4 = xs[16];
                    float I = I1 + I2 + I3 + I4, Rs = R1 + R2 + R3 + R4;
                    k_s[0]  = Rs * c_mu - (c_xi + c_mu) * M;
                    k_s[1]  = c_mu * (1.f - Rs) + c_xi * M - c_mu * S1 - bb1 * I * S1;
                    k_s[2]  = bb1 * I * S1 - (c_mu + c_sig) * E1;
                    k_s[3]  = bb2 * I * S2 - (c_mu + c_sig) * E2;
                    k_s[4]  = bb3 * I * S3 - (c_mu + c_sig) * E3;
                    k_s[5]  = bb4 * I * S4 - (c_mu + c_sig) * E4;
                    k_s[6]  = c_sig * E1 - (c_nu + c_mu) * I1;
                    k_s[7]  = c_sig * E2 - (c_nu + c_mu) * I2;
                    k_s[8]  = c_sig * E3 - (c_nu + c_mu) * I3;
                    k_s[9]  = c_sig * E4 - (c_nu + c_mu) * I4;
                    k_s[10] = c_nu * I1 - (c_mu + c_gam) * R1;
                    k_s[11] = c_nu * I2 - (c_mu + c_gam) * R2;
                    k_s[12] = c_nu * I3 - (c_mu + c_gam) * R3;
                    k_s[13] = c_nu * I4 - (c_mu + c_gam) * R4;
                    k_s[14] = c_gam * R1 - c_mu * S2 - bb2 * I * S2;
                    k_s[15] = c_gam * R2 - c_mu * S3 - bb3 * I * S3;
                    k_s[16] = c_gam * (R3 + R4) - c_mu * S4 - bb4 * I * S4;
                }

                // ---- h1 consume: own 32 words, count==32 -> read+reset ----
                if (t < SLC) {
                    u64* p = hacc1 + blk * SLC + t;
                    u64 w; int it = 0;
                    do { w = rmw_read(p); } while ((w & 0xFFFFu) != 32u && ++it < POLL_CAP);
                    reset_word(p);
                    asm volatile("s_waitcnt vmcnt(0)" ::: "memory");
                    long long val = ((long long)w) >> 16;
                    h1_s[t] = softplus_f((float)val * INV_H + bhc[0]);
                }
                __syncthreads();                                   // B3

                // ---- h2 partial adds + consume ----
                {
                    float p0 = 0.f, p1 = 0.f;
                    #pragma unroll
                    for (int q = 0; q < 8; q++) {
                        float4 z = *(const float4*)(h1_s + q * 4);
                        p0 = fmaf(wc2a[q].x, z.x, p0); p0 = fmaf(wc2a[q].y, z.y, p0);
                        p0 = fmaf(wc2a[q].z, z.z, p0); p0 = fmaf(wc2a[q].w, z.w, p0);
                        p1 = fmaf(wc2b[q].x, z.x, p1); p1 = fmaf(wc2b[q].y, z.y, p1);
                        p1 = fmaf(wc2b[q].z, z.z, p1); p1 = fmaf(wc2b[q].w, z.w, p1);
                    }
                    acc_add(hacc2 + t, p0, SCALE_H);
                    acc_add(hacc2 + t + 512, p1, SCALE_H);
                }
                if (t < SLC) {
                    u64* p = hacc2 + blk * SLC + t;
                    u64 w; int it = 0;
                    do { w = rmw_read(p); } while ((w & 0xFFFFu) != 32u && ++it < POLL_CAP);
                    reset_word(p);
                    asm volatile("s_waitcnt vmcnt(0)" ::: "memory");
                    long long val = ((long long)w) >> 16;
                    h2_s[t] = softplus_f((float)val * INV_H + bhc[1]);
                }
                __syncthreads();                                   // B4

                // ---- h3 partial adds (weights from LDS, col-major) ----
                {
                    float p0 = 0.f, p1 = 0.f;
                    #pragma unroll
                    for (int j = 0; j < SLC; j++) {
                        float hv = h2_s[j];
                        p0 = fmaf(wh3c[j * WID + t],       hv, p0);
                        p1 = fmaf(wh3c[j * WID + t + 512], hv, p1);
                    }
                    acc_add(hacc3 + t, p0, SCALE_H);
                    acc_add(hacc3 + t + 512, p1, SCALE_H);
                }
                // Wl stripe prefetch (t<256): row t, cols [blk*32,+32) — L2-hot
                float4 wvL[8];
                if (t < NH) {
                    const float* wp = Wl + (size_t)t * WID + blk * SLC;
                    #pragma unroll
                    for (int q = 0; q < 8; q++) wvL[q] = *(const float4*)(wp + q * 4);
                }
                if (t < SLC) {
                    u64* p = hacc3 + blk * SLC + t;
                    u64 w; int it = 0;
                    do { w = rmw_read(p); } while ((w & 0xFFFFu) != 32u && ++it < POLL_CAP);
                    reset_word(p);
                    asm volatile("s_waitcnt vmcnt(0)" ::: "memory");
                    long long val = ((long long)w) >> 16;
                    h3_s[t] = softplus_f((float)val * INV_H + bhc[2]);
                }
                __syncthreads();                                   // B5

                // ---- dh: partial adds (t<256) + running-total consume ----
                if (t < NH) {
                    float p = 0.f;
                    #pragma unroll
                    for (int q = 0; q < 8; q++) {
                        float4 z = *(const float4*)(h3_s + q * 4);
                        p = fmaf(wvL[q].x, z.x, p); p = fmaf(wvL[q].y, z.y, p);
                        p = fmaf(wvL[q].z, z.z, p); p = fmaf(wvL[q].w, z.w, p);
                    }
                    acc_add(dhacc + t, p, SCALE_D);

                    u64* dp = dhacc + t;
                    const u32 tgt = (32u * sidx) & 0xFFFFu;
                    u64 w; int it = 0;
                    do { w = rmw_read(dp); } while ((u32)(w & 0xFFFFu) != tgt && ++it < POLL_CAP);
                    long long val = ((long long)w) >> 16;
                    long long diff = val - prev_dh;
                    prev_dh = val;
                    float accv = (float)diff * INV_D;
                    k_s[NSTATE + t] = scale0 * tanhf(0.01f * (accv + blr));
                }
                __syncthreads();                                   // B6
                if (t < NX) yn_s[t] = fmaf(wgt, k_s[t], yn_s[t]);
            } // stages

            __syncthreads();
            if (t < NX) y_s[t] = yn_s[t];
            __syncthreads();
        } // substeps

        if (blk == 0) {
            if (t < NSTATE) out[(iv + 1) * NSTATE + t] = y_s[t];
            if (t < NH)     out[NT * NSTATE + (iv + 1) * NH + t] = y_s[NSTATE + t];
        }
    } // intervals
}

extern "C" void kernel_launch(void* const* d_in, const int* in_sizes, int n_in,
                              void* d_out, int out_size, void* d_ws, size_t ws_size,
                              hipStream_t stream) {
    const float* ts    = (const float*)d_in[0];
    const float* W0    = (const float*)d_in[1];
    const float* b0    = (const float*)d_in[2];
    const float* Wh    = (const float*)d_in[3];
    const float* bh    = (const float*)d_in[4];
    const float* Wl    = (const float*)d_in[5];
    const float* bl    = (const float*)d_in[6];
    const float* betaW = (const float*)d_in[7];
    const float* betab = (const float*)d_in[8];
    const float* hvec  = (const float*)d_in[9];
    const float* scale = (const float*)d_in[10];
    const float* y0log = (const float*)d_in[11];
    float* out = (float*)d_out;

    u64*      hacc1 = (u64*)d_ws;                         // 1024*8 = 8 KB
    u64*      hacc2 = (u64*)((char*)d_ws + 8192);         // 8 KB
    u64*      hacc3 = (u64*)((char*)d_ws + 16384);        // 8 KB
    u64*      dhacc = (u64*)((char*)d_ws + 24576);        // 256*8 = 2 KB
    unsigned* ctrl  = (unsigned*)((char*)d_ws + 26624);   // cnt[8], winner

    // allow 128KB dynamic LDS (h3 column-stripe weights)
    static int lds_set = 0;
    if (!lds_set) {
        hipFuncSetAttribute((const void*)ode_kernel,
                            hipFuncAttributeMaxDynamicSharedMemorySize, 131072);
        lds_set = 1;
    }

    // zero accumulators + counters + election state
    hipMemsetAsync(d_ws, 0, 26624 + 64, stream);
    hipLaunchKernelGGL(ode_kernel, dim3(NLAUNCH), dim3(BS), 131072, stream,
                       ts, W0, b0, Wh, bh, Wl, bl, betaW, betab, hvec, scale,
                       y0log, out, hacc1, hacc2, hacc3, dhacc, ctrl);
}

// Round 12
// 21148.122 us; speedup vs baseline: 1.2076x; 1.1234x over previous
//
#include <hip/hip_runtime.h>
#include <math.h>

#define NBLK    32          // worker blocks, all on ONE XCD (its 32 CUs)
#define NLAUNCH 256         // launched blocks; non-elected exit immediately
#define BS      512
#define NSTATE  17
#define NH      256
#define NX      273         // NH + NSTATE
#define WID     1024
#define NT      64
#define NSUB    8
#define SLC     32          // activation slice per block = WID/NBLK
#define POLL_CAP 2000000    // fail fast instead of hanging

// packed partial word: {cnt:8 | (q0+B):28 | (q1+B):28}, q = round(p * 2^15)
#define SCALE_P 32768.0f
#define INV_P   3.0517578125e-5f
#define BIAS_P  (1LL << 22)
#define BIAS32  (32LL << 22)
// dh running-total word: {cnt:16 | int48 value}, scale 2^20
#define SCALE_D 1048576.0f
#define INV_D   9.5367431640625e-7f

typedef unsigned long long u64;
typedef unsigned int u32;

__device__ __forceinline__ float softplus_f(float v) {
    return fmaxf(v, 0.f) + log1pf(expf(-fabsf(v)));
}

// ---- counter-embedded fixed-point accumulate exchange (same-XCD L2) -------
// Col-parallel partial sums through the L2 atomic units (never stale,
// R5/R9/R11-proven; int adds associative -> deterministic). R11 lessons:
// (a) 32K adds/sync congest the atomic pipes -> pack TWO adjacent rows per
//     word (16K adds, fields bias-shifted so no cross-field carry);
// (b) consumer reset+vmcnt was a serial RTT -> PARITY double-buffers, reset
//     is fire-and-forget (fenced transitively: owner's next-sync vmcnt(0)
//     orders it; other blocks reach stage s+2 adds only after s+1's dh sync).
// count field == 32 IS the arrival signal -- the add self-announces.
__device__ __forceinline__ void acc_pack(u64* p, float p0, float p1) {
    long long q0 = llrintf(p0 * SCALE_P) + BIAS_P;
    long long q1 = llrintf(p1 * SCALE_P) + BIAS_P;
    u64 w = 1ULL + ((u64)q0 << 8) + ((u64)q1 << 36);
    asm volatile("global_atomic_add_x2 %0, %1, off" :: "v"(p), "v"(w) : "memory");
}
__device__ __forceinline__ void acc_dh(u64* p, float v) {
    long long q = llrintf(v * SCALE_D);
    u64 w = ((u64)q << 16) + 1ULL;
    asm volatile("global_atomic_add_x2 %0, %1, off" :: "v"(p), "v"(w) : "memory");
}
__device__ __forceinline__ u64 rmw_read(const u64* p) {
    u64 w;
    asm volatile("global_atomic_add_x2 %0, %1, %2, off sc0\n\t"
                 "s_waitcnt vmcnt(0)"
                 : "=&v"(w) : "v"(p), "v"(0ULL) : "memory");
    return w;
}
__device__ __forceinline__ void reset_async(u64* p) {   // no fence: parity-safe
    asm volatile("global_atomic_swap_x2 %0, %1, off" :: "v"(p), "v"(0ULL) : "memory");
}

extern "C" __global__ __launch_bounds__(BS, 1) void ode_kernel(
    const float* __restrict__ ts,   const float* __restrict__ W0,
    const float* __restrict__ b0,   const float* __restrict__ Wh,
    const float* __restrict__ bh,   const float* __restrict__ Wl,
    const float* __restrict__ bl,   const float* __restrict__ betaW,
    const float* __restrict__ betab,const float* __restrict__ hvec,
    const float* __restrict__ scale,const float* __restrict__ y0log,
    float* __restrict__ out, u64* hacc1, u64* hacc2, u64* hacc3,
    u64* dhacc, unsigned* ctrl)
{
    const int t = threadIdx.x;

    __shared__ int role_sh;
    __shared__ __align__(16) float y_s[NX];
    __shared__ __align__(16) float yn_s[NX];
    __shared__ __align__(16) float xm[NX];    // MLP order: [h(256), state(17)]
    __shared__ __align__(16) float k_s[NX];
    __shared__ __align__(16) float z1_s[SLC];
    __shared__ __align__(16) float h1_s[SLC];
    __shared__ __align__(16) float h2_s[SLC];
    __shared__ __align__(16) float h3_s[SLC];
    __shared__ float red[8];
    __shared__ float dt_sh;
    extern __shared__ float wh3c[];  // 128KB: col-major [j][r] = Wh[2][r][blk*32+j]

    // ---- XCD election (MALL atomics, one-time): first XCD with NBLK blocks
    // wins. ~134KB LDS -> 1 block/CU; all 256 launched blocks co-resident.
    if (t == 0) {
        int xcd;
        asm volatile("s_getreg_b32 %0, hwreg(HW_REG_XCC_ID)" : "=s"(xcd));
        xcd &= 7;
        unsigned rk = atomicAdd(&ctrl[xcd], 1u);
        if (rk == NBLK - 1) atomicCAS(&ctrl[8], 0u, (unsigned)(xcd + 1));
        unsigned w; int it = 0;
        do {
            w = __hip_atomic_load(&ctrl[8], __ATOMIC_RELAXED, __HIP_MEMORY_SCOPE_AGENT);
        } while (w == 0u && ++it < POLL_CAP);
        role_sh = (w != 0u && xcd == (int)w - 1 && rk < NBLK) ? (int)rk : -1;
    }
    __syncthreads();
    const int blk = role_sh;
    if (blk < 0) return;

    const float scale0 = scale[0];
    const float betab0 = betab[0];

    const int rowH = t >> 4, laneH = t & 15;   // 32 rows x 16 lanes (z1 only)
    const int growH = blk * SLC + rowH;
    const int r0 = 2 * t, r1 = 2 * t + 1;      // packed output-row pair

    // ---- loop-invariant scalars ----
    const float b0r    = b0[growH];
    const float betaWr = (t < NH) ? betaW[t] : 0.f;
    const float blr    = (t < NH) ? bl[t] : 0.f;
    float bhc[3];      // consume biases: rows blk*32+2t, +2t+1 handled below
    float bhc_o[3];
    if (t < 16) {
        bhc[0]   = bh[blk * SLC + 2 * t];
        bhc_o[0] = bh[blk * SLC + 2 * t + 1];
        bhc[1]   = bh[WID + blk * SLC + 2 * t];
        bhc_o[1] = bh[WID + blk * SLC + 2 * t + 1];
        bhc[2]   = bh[2 * WID + blk * SLC + 2 * t];
        bhc_o[2] = bh[2 * WID + blk * SLC + 2 * t + 1];
    }

    // ---- weights ----
    float w0r[18];     // W0 row-slice (z1 local)
    {
        const float* w0p = W0 + (size_t)growH * NX;
        #pragma unroll
        for (int i = 0; i < 18; i++) {
            int c = laneH + i * 16;
            w0r[i] = (c < NX) ? w0p[c] : 0.f;
        }
    }
    // h1/h2 COLUMN stripes in VGPRs: thread t owns rows {2t, 2t+1},
    // cols [blk*32,+32): 4x8 float4 = 128 VGPR.
    float4 wc1a[8], wc1b[8], wc2a[8], wc2b[8];
    {
        const float* base0 = Wh + (size_t)r0 * WID + blk * SLC;
        const float* base1 = Wh + (size_t)r1 * WID + blk * SLC;
        #pragma unroll
        for (int q = 0; q < 8; q++) {
            wc1a[q] = *(const float4*)(base0 + q * 4);
            wc1b[q] = *(const float4*)(base1 + q * 4);
            wc2a[q] = *(const float4*)(base0 + (size_t)WID * WID + q * 4);
            wc2b[q] = *(const float4*)(base1 + (size_t)WID * WID + q * 4);
        }
    }
    // h3 column stripe in LDS, col-major [j][r]
    {
        const float* src = Wh + 2 * (size_t)WID * WID;
        for (int i = t; i < WID * 8; i += BS) {
            int r = i >> 3, q = i & 7;
            float4 v = *(const float4*)(src + (size_t)r * WID + blk * SLC + q * 4);
            wh3c[(q * 4 + 0) * WID + r] = v.x;
            wh3c[(q * 4 + 1) * WID + r] = v.y;
            wh3c[(q * 4 + 2) * WID + r] = v.z;
            wh3c[(q * 4 + 3) * WID + r] = v.w;
        }
    }

    // ---- y0 = [softmax(y0_log), hvec] ----
    if (t < NSTATE) {
        float m = -1e30f;
        for (int j = 0; j < NSTATE; j++) m = fmaxf(m, y0log[j]);
        float ssum = 0.f;
        for (int j = 0; j < NSTATE; j++) ssum += expf(y0log[j] - m);
        y_s[t] = expf(y0log[t] - m) / ssum;
    }
    if (t < NH) y_s[NSTATE + t] = hvec[t];
    __syncthreads();

    if (blk == 0) {
        if (t < NSTATE) out[t] = y_s[t];
        if (t < NH)     out[NT * NSTATE + t] = y_s[NSTATE + t];
    }

    const float c_xi = 13.f / 12.f, c_mu = 0.041f / 12.f, c_sig = 91.f / 12.f,
                c_nu = 36.f / 12.f, c_gam = 1.8f / 12.f;

    long long prev_dh = 0;   // running-total tracker for dh word t (t<NH)
    unsigned sidx = 0;       // global stage counter

    for (int iv = 0; iv < NT - 1; iv++) {
        if (t == 0) dt_sh = (ts[iv + 1] - ts[iv]) * (1.f / NSUB);
        __syncthreads();
        const float dt = dt_sh;

        for (int sub = 0; sub < NSUB; sub++) {
            if (t < NX) yn_s[t] = y_s[t];

            for (int s = 0; s < 4; s++) {
                const float a   = (s == 0) ? 0.f : ((s == 3) ? 1.f : 0.5f);
                const float wgt = ((s == 0) || (s == 3)) ? dt * (1.f / 6.f) : dt * (1.f / 3.f);
                const float adt = a * dt;
                ++sidx;
                const int par = (int)(sidx & 1u);       // parity buffer select
                u64* h1p = hacc1 + par * 512;
                u64* h2p = hacc2 + par * 512;
                u64* h3p = hacc3 + par * 512;

                // ---- stage input, built directly in MLP order [h, state] ----
                if (t < NX) {
                    const int src = (t < NH) ? (NSTATE + t) : (t - NH);
                    float v = y_s[src];
                    if (s != 0) v = fmaf(adt, k_s[src], v);
                    xm[t] = v;
                }
                __syncthreads();                                   // B1

                // ---- z1 slice (local): 32 rows x 16 lanes ----
                {
                    float acc = 0.f;
                    #pragma unroll
                    for (int i = 0; i < 18; i++) {
                        int c = laneH + i * 16;
                        if (c < NX) acc = fmaf(w0r[i], xm[c], acc);
                    }
                    #pragma unroll
                    for (int m = 1; m < 16; m <<= 1) acc += __shfl_xor(acc, m, 16);
                    if (laneH == 0) z1_s[rowH] = softplus_f(acc + b0r);
                }
                if (t < NH) {      // beta head partial
                    float p = betaWr * xm[t];
                    #pragma unroll
                    for (int m = 1; m < 64; m <<= 1) p += __shfl_xor(p, m, 64);
                    if ((t & 63) == 0) red[t >> 6] = p;
                }
                __syncthreads();                                   // B2

                // ---- h1 packed partial adds (fire-and-forget) ----
                {
                    float p0 = 0.f, p1 = 0.f;
                    #pragma unroll
                    for (int q = 0; q < 8; q++) {
                        float4 z = *(const float4*)(z1_s + q * 4);
                        p0 = fmaf(wc1a[q].x, z.x, p0); p0 = fmaf(wc1a[q].y, z.y, p0);
                        p0 = fmaf(wc1a[q].z, z.z, p0); p0 = fmaf(wc1a[q].w, z.w, p0);
                        p1 = fmaf(wc1b[q].x, z.x, p1); p1 = fmaf(wc1b[q].y, z.y, p1);
                        p1 = fmaf(wc1b[q].z, z.z, p1); p1 = fmaf(wc1b[q].w, z.w, p1);
                    }
                    acc_pack(h1p + t, p0, p1);
                }

                // ---- dstate (redundant, one thread; overlaps h1 flight) ----
                if (t == 256) {
                    const float* xs = xm + NH;
                    float sd  = red[0] + red[1] + red[2] + red[3] + betab0;
                    float bb1 = 8.f / (1.f + expf(-sd)) + 25.f;
                    float bb2 = 0.5f * bb1, bb3 = 0.35f * bb1, bb4 = 0.25f * bb1;
                    float M  = xs[0],  S1 = xs[1],  E1 = xs[2],  E2 = xs[3];
                    float E3 = xs[4],  E4 = xs[5],  I1 = xs[6],  I2 = xs[7];
                    float I3 = xs[8],  I4 = xs[9],  R1 = xs[10], R2 = xs[11];
                    float R3 = xs[12], R4 = xs[13], S2 = xs[14], S3 = xs[15];
                    float S4 = xs[16];
                    float I = I1 + I2 + I3 + I4, Rs = R1 + R2 + R3 + R4;
                    k_s[0]  = Rs * c_mu - (c_xi + c_mu) * M;
                    k_s[1]  = c_mu * (1.f - Rs) + c_xi * M - c_mu * S1 - bb1 * I * S1;
                    k_s[2]  = bb1 * I * S1 - (c_mu + c_sig) * E1;
                    k_s[3]  = bb2 * I * S2 - (c_mu + c_sig) * E2;
                    k_s[4]  = bb3 * I * S3 - (c_mu + c_sig) * E3;
                    k_s[5]  = bb4 * I * S4 - (c_mu + c_sig) * E4;
                    k_s[6]  = c_sig * E1 - (c_nu + c_mu) * I1;
                    k_s[7]  = c_sig * E2 - (c_nu + c_mu) * I2;
                    k_s[8]  = c_sig * E3 - (c_nu + c_mu) * I3;
                    k_s[9]  = c_sig * E4 - (c_nu + c_mu) * I4;
                    k_s[10] = c_nu * I1 - (c_mu + c_gam) * R1;
                    k_s[11] = c_nu * I2 - (c_mu + c_gam) * R2;
                    k_s[12] = c_nu * I3 - (c_mu + c_gam) * R3;
                    k_s[13] = c_nu * I4 - (c_mu + c_gam) * R4;
                    k_s[14] = c_gam * R1 - c_mu * S2 - bb2 * I * S2;
                    k_s[15] = c_gam * R2 - c_mu * S3 - bb3 * I * S3;
                    k_s[16] = c_gam * (R3 + R4) - c_mu * S4 - bb4 * I * S4;
                }

                // ---- h1 consume: 16 packed words, count==32 -> unpack ----
                if (t < 16) {
                    u64* p = h1p + blk * 16 + t;
                    u64 w; int it = 0;
                    do { w = rmw_read(p); } while ((w & 0xFFu) != 32u && ++it < POLL_CAP);
                    reset_async(p);
                    long long v0 = (long long)((w >> 8) & 0xFFFFFFFULL) - BIAS32;
                    long long v1 = (long long)(w >> 36) - BIAS32;
                    h1_s[2 * t]     = softplus_f((float)v0 * INV_P + bhc[0]);
                    h1_s[2 * t + 1] = softplus_f((float)v1 * INV_P + bhc_o[0]);
                }
                __syncthreads();                                   // B3

                // ---- h2 packed adds + consume ----
                {
                    float p0 = 0.f, p1 = 0.f;
                    #pragma unroll
                    for (int q = 0; q < 8; q++) {
                        float4 z = *(const float4*)(h1_s + q * 4);
                        p0 = fmaf(wc2a[q].x, z.x, p0); p0 = fmaf(wc2a[q].y, z.y, p0);
                        p0 = fmaf(wc2a[q].z, z.z, p0); p0 = fmaf(wc2a[q].w, z.w, p0);
                        p1 = fmaf(wc2b[q].x, z.x, p1); p1 = fmaf(wc2b[q].y, z.y, p1);
                        p1 = fmaf(wc2b[q].z, z.z, p1); p1 = fmaf(wc2b[q].w, z.w, p1);
                    }
                    acc_pack(h2p + t, p0, p1);
                }
                if (t < 16) {
                    u64* p = h2p + blk * 16 + t;
                    u64 w; int it = 0;
                    do { w = rmw_read(p); } while ((w & 0xFFu) != 32u && ++it < POLL_CAP);
                    reset_async(p);
                    long long v0 = (long long)((w >> 8) & 0xFFFFFFFULL) - BIAS32;
                    long long v1 = (long long)(w >> 36) - BIAS32;
                    h2_s[2 * t]     = softplus_f((float)v0 * INV_P + bhc[1]);
                    h2_s[2 * t + 1] = softplus_f((float)v1 * INV_P + bhc_o[1]);
                }
                __syncthreads();                                   // B4

                // ---- h3 packed adds (weights from LDS, col-major) ----
                {
                    float p0 = 0.f, p1 = 0.f;
                    #pragma unroll
                    for (int j = 0; j < SLC; j++) {
                        float hv = h2_s[j];
                        float2 wv = *(const float2*)(wh3c + j * WID + r0);
                        p0 = fmaf(wv.x, hv, p0);
                        p1 = fmaf(wv.y, hv, p1);
                    }
                    acc_pack(h3p + t, p0, p1);
                }
                // Wl stripe prefetch (t<256): row t, cols [blk*32,+32) — L2-hot
                float4 wvL[8];
                if (t < NH) {
                    const float* wp = Wl + (size_t)t * WID + blk * SLC;
                    #pragma unroll
                    for (int q = 0; q < 8; q++) wvL[q] = *(const float4*)(wp + q * 4);
                }
                if (t < 16) {
                    u64* p = h3p + blk * 16 + t;
                    u64 w; int it = 0;
                    do { w = rmw_read(p); } while ((w & 0xFFu) != 32u && ++it < POLL_CAP);
                    reset_async(p);
                    long long v0 = (long long)((w >> 8) & 0xFFFFFFFULL) - BIAS32;
                    long long v1 = (long long)(w >> 36) - BIAS32;
                    h3_s[2 * t]     = softplus_f((float)v0 * INV_P + bhc[2]);
                    h3_s[2 * t + 1] = softplus_f((float)v1 * INV_P + bhc_o[2]);
                }
                __syncthreads();                                   // B5

                // ---- dh: partial adds (t<256) + running-total consume ----
                if (t < NH) {
                    float p = 0.f;
                    #pragma unroll
                    for (int q = 0; q < 8; q++) {
                        float4 z = *(const float4*)(h3_s + q * 4);
                        p = fmaf(wvL[q].x, z.x, p); p = fmaf(wvL[q].y, z.y, p);
                        p = fmaf(wvL[q].z, z.z, p); p = fmaf(wvL[q].w, z.w, p);
                    }
                    acc_dh(dhacc + t, p);

                    u64* dp = dhacc + t;
                    const u32 tgt = (32u * sidx) & 0xFFFFu;
                    u64 w; int it = 0;
                    do { w = rmw_read(dp); } while ((u32)(w & 0xFFFFu) != tgt && ++it < POLL_CAP);
                    long long val = ((long long)w) >> 16;
                    long long diff = val - prev_dh;
                    prev_dh = val;
                    float accv = (float)diff * INV_D;
                    k_s[NSTATE + t] = scale0 * tanhf(0.01f * (accv + blr));
                }
                __syncthreads();                                   // B6
                if (t < NX) yn_s[t] = fmaf(wgt, k_s[t], yn_s[t]);
            } // stages

            __syncthreads();
            if (t < NX) y_s[t] = yn_s[t];
            __syncthreads();
        } // substeps

        if (blk == 0) {
            if (t < NSTATE) out[(iv + 1) * NSTATE + t] = y_s[t];
            if (t < NH)     out[NT * NSTATE + (iv + 1) * NH + t] = y_s[NSTATE + t];
        }
    } // intervals
}

extern "C" void kernel_launch(void* const* d_in, const int* in_sizes, int n_in,
                              void* d_out, int out_size, void* d_ws, size_t ws_size,
                              hipStream_t stream) {
    const float* ts    = (const float*)d_in[0];
    const float* W0    = (const float*)d_in[1];
    const float* b0    = (const float*)d_in[2];
    const float* Wh    = (const float*)d_in[3];
    const float* bh    = (const float*)d_in[4];
    const float* Wl    = (const float*)d_in[5];
    const float* bl    = (const float*)d_in[6];
    const float* betaW = (const float*)d_in[7];
    const float* betab = (const float*)d_in[8];
    const float* hvec  = (const float*)d_in[9];
    const float* scale = (const float*)d_in[10];
    const float* y0log = (const float*)d_in[11];
    float* out = (float*)d_out;

    // parity-doubled packed accumulators: 2 x 512 u64 each
    u64*      hacc1 = (u64*)d_ws;                         // 8 KB
    u64*      hacc2 = (u64*)((char*)d_ws + 8192);         // 8 KB
    u64*      hacc3 = (u64*)((char*)d_ws + 16384);        // 8 KB
    u64*      dhacc = (u64*)((char*)d_ws + 24576);        // 2 KB
    unsigned* ctrl  = (unsigned*)((char*)d_ws + 26624);   // cnt[8], winner

    // allow 128KB dynamic LDS (h3 column-stripe weights)
    static int lds_set = 0;
    if (!lds_set) {
        hipFuncSetAttribute((const void*)ode_kernel,
                            hipFuncAttributeMaxDynamicSharedMemorySize, 131072);
        lds_set = 1;
    }

    // zero accumulators + counters + election state
    hipMemsetAsync(d_ws, 0, 26624 + 64, stream);
    hipLaunchKernelGGL(ode_kernel, dim3(NLAUNCH), dim3(BS), 131072, stream,
                       ts, W0, b0, Wh, bh, Wl, bl, betaW, betab, hvec, scale,
                       y0log, out, hacc1, hacc2, hacc3, dhacc, ctrl);
}